// Round 1
// baseline (4650.058 us; speedup 1.0000x reference)
//
#include <hip/hip_runtime.h>
#include <hip/hip_bf16.h>

// GCN graph classifier: 3x (GCNConv -> BN -> ReLU) -> sum-pool -> MLP head.
// Norm folding: msg norm (deg_s*deg_d)^-0.5 with self-loops ->
//   Hs[i] = (x[i]@W.T + b) * rdeg[i]
//   agg[d] = Hs[d] + sum_{edges s->d} Hs[s]        (self-loop term = Hs[d], scaled later)
//   conv_out[d] = rdeg[d] * agg[d]                 (rdeg factor folded into BN pass)

#define NN 100000
#define NE 1600000
#define INF_ 128
#define HF 64
#define OUTF 10
#define NG 128

__global__ void k_deg(const int* __restrict__ dst, float* __restrict__ deg, int E) {
    int e = blockIdx.x * 256 + threadIdx.x;
    if (e < E) atomicAdd(&deg[dst[e]], 1.0f);
}

__global__ void k_rdeg(float* __restrict__ deg, int n) {
    int i = blockIdx.x * 256 + threadIdx.x;
    if (i < n) deg[i] = rsqrtf(deg[i] + 1.0f);  // +1 = self loop; deg>=1 so no inf guard needed
}

// One thread per node row. W rows read with uniform indices -> scalar loads.
template<int K>
__global__ __launch_bounds__(256) void k_gemm(const float* __restrict__ X,
                                              const float* __restrict__ W,
                                              const float* __restrict__ bias,
                                              const float* __restrict__ rdeg,
                                              float* __restrict__ Hs,
                                              float* __restrict__ A, int n) {
    int row = blockIdx.x * 256 + threadIdx.x;
    if (row >= n) return;
    float acc[HF];
#pragma unroll
    for (int o = 0; o < HF; ++o) acc[o] = 0.f;
    const float* xr = X + (size_t)row * K;
    for (int kk = 0; kk < K; kk += 4) {
        float4 xv = *(const float4*)(xr + kk);
#pragma unroll
        for (int o = 0; o < HF; ++o) {
            float4 wv = *(const float4*)(W + o * K + kk);  // uniform -> s_load_dwordx4
            acc[o] = fmaf(xv.x, wv.x, fmaf(xv.y, wv.y, fmaf(xv.z, wv.z, fmaf(xv.w, wv.w, acc[o]))));
        }
    }
    float r = rdeg[row];
    float4* hs = (float4*)(Hs + (size_t)row * HF);
    float4* aa = (float4*)(A + (size_t)row * HF);
#pragma unroll
    for (int o = 0; o < HF; o += 4) {
        float4 v = make_float4((bias[o] + acc[o]) * r, (bias[o + 1] + acc[o + 1]) * r,
                               (bias[o + 2] + acc[o + 2]) * r, (bias[o + 3] + acc[o + 3]) * r);
        hs[o >> 2] = v;
        aa[o >> 2] = v;
    }
}

// 16 threads per edge, float4 gather + 4 scalar atomics each.
__global__ void k_edges(const int* __restrict__ src, const int* __restrict__ dst,
                        const float* __restrict__ Hs, float* __restrict__ A, int E) {
    int t = blockIdx.x * 256 + threadIdx.x;
    int e = t >> 4;
    if (e >= E) return;
    int c = (t & 15) * 4;
    int s = src[e], d = dst[e];
    float4 v = *(const float4*)(Hs + (size_t)s * HF + c);
    float* p = A + (size_t)d * HF + c;
    atomicAdd(p + 0, v.x);
    atomicAdd(p + 1, v.y);
    atomicAdd(p + 2, v.z);
    atomicAdd(p + 3, v.w);
}

// Column sums / sumsqs of v = rdeg[r]*A[r][c] over all rows.
__global__ void k_stats(const float* __restrict__ A, const float* __restrict__ rdeg,
                        float* __restrict__ stats, int n) {
    __shared__ float ls[4][HF], lq[4][HF];
    int c = threadIdx.x & 63, w = threadIdx.x >> 6;
    float s = 0.f, q = 0.f;
    for (int r = blockIdx.x * 4 + w; r < n; r += gridDim.x * 4) {
        float v = rdeg[r] * A[(size_t)r * HF + c];
        s += v;
        q += v * v;
    }
    ls[w][c] = s;
    lq[w][c] = q;
    __syncthreads();
    if (w == 0) {
        float S = ls[0][c] + ls[1][c] + ls[2][c] + ls[3][c];
        float Q = lq[0][c] + lq[1][c] + lq[2][c] + lq[3][c];
        atomicAdd(&stats[c], S);
        atomicAdd(&stats[HF + c], Q);
    }
}

__global__ void k_bnparams(float* __restrict__ stats, const float* __restrict__ g,
                           const float* __restrict__ be, float n) {
    int c = threadIdx.x;  // 64 threads
    float mu = stats[c] / n;
    float var = stats[HF + c] / n - mu * mu;  // biased var, matches jnp.var(0)
    float a = g[c] * rsqrtf(var + 1e-5f);
    stats[128 + c] = a;
    stats[192 + c] = be[c] - mu * a;
}

__global__ void k_bnapply(const float* __restrict__ A, const float* __restrict__ rdeg,
                          const float* __restrict__ stats, float* __restrict__ X, int n) {
    int t = blockIdx.x * 256 + threadIdx.x;
    if (t >= n * HF) return;
    int c = t & 63, r = t >> 6;
    float v = rdeg[r] * A[t];
    X[t] = fmaxf(fmaf(stats[128 + c], v, stats[192 + c]), 0.0f);
}

__global__ void k_pool(const float* __restrict__ X, const int* __restrict__ batch,
                       float* __restrict__ pool, int n) {
    int t = blockIdx.x * 256 + threadIdx.x;
    if (t >= n * HF) return;
    int c = t & 63, r = t >> 6;
    atomicAdd(&pool[(size_t)batch[r] * HF + c], X[t]);
}

__global__ void k_cls(const float* __restrict__ pool, const float* __restrict__ Wc1,
                      const float* __restrict__ bc1, const float* __restrict__ Wc2,
                      const float* __restrict__ bc2, float* __restrict__ out) {
    __shared__ float pl[HF], hr[HF];
    int g = blockIdx.x, c = threadIdx.x;
    pl[c] = pool[g * HF + c];
    __syncthreads();
    float h = bc1[c];
#pragma unroll
    for (int k = 0; k < HF; ++k) h = fmaf(pl[k], Wc1[c * HF + k], h);
    hr[c] = fmaxf(h, 0.f);
    __syncthreads();
    if (c < OUTF) {
        float o = bc2[c];
#pragma unroll
        for (int k = 0; k < HF; ++k) o = fmaf(hr[k], Wc2[c * HF + k], o);
        out[g * OUTF + c] = o;
    }
}

extern "C" void kernel_launch(void* const* d_in, const int* in_sizes, int n_in,
                              void* d_out, int out_size, void* d_ws, size_t ws_size,
                              hipStream_t stream) {
    const float* x = (const float*)d_in[0];
    const int* edge = (const int*)d_in[1];
    const int* batch = (const int*)d_in[2];
    const float* W1 = (const float*)d_in[3];
    const float* b1 = (const float*)d_in[4];
    const float* g1 = (const float*)d_in[5];
    const float* be1 = (const float*)d_in[6];
    const float* W2 = (const float*)d_in[7];
    const float* b2 = (const float*)d_in[8];
    const float* g2 = (const float*)d_in[9];
    const float* be2 = (const float*)d_in[10];
    const float* W3 = (const float*)d_in[11];
    const float* b3 = (const float*)d_in[12];
    const float* g3 = (const float*)d_in[13];
    const float* be3 = (const float*)d_in[14];
    const float* Wc1 = (const float*)d_in[15];
    const float* bc1 = (const float*)d_in[16];
    const float* Wc2 = (const float*)d_in[17];
    const float* bc2 = (const float*)d_in[18];
    float* out = (float*)d_out;

    const int* src = edge;
    const int* dst = edge + NE;

    const size_t N64 = (size_t)NN * HF;
    float* ws = (float*)d_ws;
    float* buf0 = ws;                // N*64  (Hs; also BN output)
    float* buf1 = ws + N64;          // N*64  (A aggregation)
    float* rdeg = ws + 2 * N64;      // N
    float* stats = rdeg + NN;        // 256: sum|sumsq|a|b2
    float* pool = stats + 256;       // NG*64

    hipMemsetAsync(rdeg, 0, NN * sizeof(float), stream);
    k_deg<<<(NE + 255) / 256, 256, 0, stream>>>(dst, rdeg, NE);
    k_rdeg<<<(NN + 255) / 256, 256, 0, stream>>>(rdeg, NN);

    const float* W[3] = {W1, W2, W3};
    const float* bb[3] = {b1, b2, b3};
    const float* gg[3] = {g1, g2, g3};
    const float* bebe[3] = {be1, be2, be3};

    for (int l = 0; l < 3; ++l) {
        if (l == 0)
            k_gemm<INF_><<<(NN + 255) / 256, 256, 0, stream>>>(x, W[0], bb[0], rdeg, buf0, buf1, NN);
        else
            k_gemm<HF><<<(NN + 255) / 256, 256, 0, stream>>>(buf0, W[l], bb[l], rdeg, buf0, buf1, NN);
        k_edges<<<(NE * 16 + 255) / 256, 256, 0, stream>>>(src, dst, buf0, buf1, NE);
        hipMemsetAsync(stats, 0, 128 * sizeof(float), stream);
        k_stats<<<1024, 256, 0, stream>>>(buf1, rdeg, stats, NN);
        k_bnparams<<<1, 64, 0, stream>>>(stats, gg[l], bebe[l], (float)NN);
        k_bnapply<<<((int)N64 + 255) / 256, 256, 0, stream>>>(buf1, rdeg, stats, buf0, NN);
    }

    hipMemsetAsync(pool, 0, (size_t)NG * HF * sizeof(float), stream);
    k_pool<<<((int)N64 + 255) / 256, 256, 0, stream>>>(buf0, batch, pool, NN);
    k_cls<<<NG, HF, 0, stream>>>(pool, Wc1, bc1, Wc2, bc2, out);
}

// Round 2
// 839.491 us; speedup vs baseline: 5.5391x; 5.5391x over previous
//
#include <hip/hip_runtime.h>
#include <hip/hip_bf16.h>

// GCN graph classifier: 3x (GCNConv -> BN -> ReLU) -> sum-pool -> MLP head.
// Norm folding: msg norm (deg_s*deg_d)^-0.5 with self-loops ->
//   Hs[i] = (x[i]@W.T + b) * rdeg[i]
//   agg[d] = Hs[d] + sum_{in-edges s->d} Hs[s]     (CSR gather, no atomics)
//   conv_out[d] = rdeg[d] * agg[d]                 (rdeg factor folded into BN pass)
// CSR (by dst) built once per call: histogram -> 3-kernel exclusive scan -> scatter.

#define NN 100000
#define NE 1600000
#define INF_ 128
#define HF 64
#define OUTF 10
#define NG 128

__global__ void k_hist(const int* __restrict__ dst, int* __restrict__ cnt, int E) {
    int e = blockIdx.x * 256 + threadIdx.x;
    if (e < E) atomicAdd(&cnt[dst[e]], 1);
}

__global__ void k_rdegi(const int* __restrict__ cnt, float* __restrict__ rdeg, int n) {
    int i = blockIdx.x * 256 + threadIdx.x;
    if (i < n) rdeg[i] = rsqrtf((float)cnt[i] + 1.0f);  // +1 = self loop
}

// Block scans 1024 elements (256 threads x 4). Writes per-element exclusive
// prefix (block-local) to ro, block total to bsum.
__global__ void k_scan1(const int* __restrict__ cnt, int* __restrict__ ro,
                        int* __restrict__ bsum, int n) {
    __shared__ int ts[256];
    int base = blockIdx.x * 1024 + threadIdx.x * 4;
    int v[4], s = 0;
#pragma unroll
    for (int k = 0; k < 4; ++k) {
        int idx = base + k;
        v[k] = (idx < n) ? cnt[idx] : 0;
        s += v[k];
    }
    ts[threadIdx.x] = s;
    __syncthreads();
    for (int off = 1; off < 256; off <<= 1) {
        int t = (threadIdx.x >= off) ? ts[threadIdx.x - off] : 0;
        __syncthreads();
        ts[threadIdx.x] += t;
        __syncthreads();
    }
    int ex = ts[threadIdx.x] - s;  // exclusive prefix of this thread's chunk
    if (threadIdx.x == 255) bsum[blockIdx.x] = ts[255];
#pragma unroll
    for (int k = 0; k < 4; ++k) {
        int idx = base + k;
        if (idx < n) ro[idx] = ex;
        ex += v[k];
    }
}

// Single block: exclusive scan of nb (<=128) block sums in place.
__global__ void k_scan2(int* __restrict__ bsum, int nb) {
    __shared__ int ts[128];
    int i = threadIdx.x;
    int v = (i < nb) ? bsum[i] : 0;
    ts[i] = v;
    __syncthreads();
    for (int off = 1; off < 128; off <<= 1) {
        int t = (i >= off) ? ts[i - off] : 0;
        __syncthreads();
        ts[i] += t;
        __syncthreads();
    }
    if (i < nb) bsum[i] = ts[i] - v;
}

__global__ void k_scan3(int* __restrict__ ro, int* __restrict__ cursor,
                        const int* __restrict__ bsum, int n, int E) {
    int i = blockIdx.x * 256 + threadIdx.x;
    if (i < n) {
        int v = ro[i] + bsum[i >> 10];
        ro[i] = v;
        cursor[i] = v;
    }
    if (i == 0) ro[n] = E;
}

__global__ void k_scatter(const int* __restrict__ src, const int* __restrict__ dst,
                          int* __restrict__ cursor, int* __restrict__ ss, int E) {
    int e = blockIdx.x * 256 + threadIdx.x;
    if (e < E) {
        int pos = atomicAdd(&cursor[dst[e]], 1);
        ss[pos] = src[e];
    }
}

// One thread per node row. W rows read with uniform indices.
template<int K>
__global__ __launch_bounds__(256) void k_gemm(const float* __restrict__ X,
                                              const float* __restrict__ W,
                                              const float* __restrict__ bias,
                                              const float* __restrict__ rdeg,
                                              float* __restrict__ Hs, int n) {
    int row = blockIdx.x * 256 + threadIdx.x;
    if (row >= n) return;
    float acc[HF];
#pragma unroll
    for (int o = 0; o < HF; ++o) acc[o] = 0.f;
    const float* xr = X + (size_t)row * K;
    for (int kk = 0; kk < K; kk += 4) {
        float4 xv = *(const float4*)(xr + kk);
#pragma unroll
        for (int o = 0; o < HF; ++o) {
            float4 wv = *(const float4*)(W + o * K + kk);
            acc[o] = fmaf(xv.x, wv.x, fmaf(xv.y, wv.y, fmaf(xv.z, wv.z, fmaf(xv.w, wv.w, acc[o]))));
        }
    }
    float r = rdeg[row];
    float4* hs = (float4*)(Hs + (size_t)row * HF);
#pragma unroll
    for (int o = 0; o < HF; o += 4) {
        hs[o >> 2] = make_float4((bias[o] + acc[o]) * r, (bias[o + 1] + acc[o + 1]) * r,
                                 (bias[o + 2] + acc[o + 2]) * r, (bias[o + 3] + acc[o + 3]) * r);
    }
}

// One wave per node, lane = channel. Coalesced 256B gathers, no atomics.
__global__ __launch_bounds__(256) void k_agg(const int* __restrict__ ro,
                                             const int* __restrict__ ss,
                                             const float* __restrict__ Hs,
                                             float* __restrict__ A, int n) {
    int node = blockIdx.x * 4 + (threadIdx.x >> 6);
    if (node >= n) return;
    int lane = threadIdx.x & 63;
    int beg = ro[node], end = ro[node + 1];
    float acc = Hs[(size_t)node * HF + lane];  // self loop
    int j = beg;
    for (; j + 3 < end; j += 4) {
        int s0 = ss[j], s1 = ss[j + 1], s2 = ss[j + 2], s3 = ss[j + 3];
        float v0 = Hs[(size_t)s0 * HF + lane];
        float v1 = Hs[(size_t)s1 * HF + lane];
        float v2 = Hs[(size_t)s2 * HF + lane];
        float v3 = Hs[(size_t)s3 * HF + lane];
        acc += v0 + v1 + v2 + v3;
    }
    for (; j < end; ++j) acc += Hs[(size_t)ss[j] * HF + lane];
    A[(size_t)node * HF + lane] = acc;
}

// Column sums / sumsqs of v = rdeg[r]*A[r][c] over all rows.
__global__ void k_stats(const float* __restrict__ A, const float* __restrict__ rdeg,
                        float* __restrict__ stats, int n) {
    __shared__ float ls[4][HF], lq[4][HF];
    int c = threadIdx.x & 63, w = threadIdx.x >> 6;
    float s = 0.f, q = 0.f;
    for (int r = blockIdx.x * 4 + w; r < n; r += gridDim.x * 4) {
        float v = rdeg[r] * A[(size_t)r * HF + c];
        s += v;
        q += v * v;
    }
    ls[w][c] = s;
    lq[w][c] = q;
    __syncthreads();
    if (w == 0) {
        atomicAdd(&stats[c], ls[0][c] + ls[1][c] + ls[2][c] + ls[3][c]);
        atomicAdd(&stats[HF + c], lq[0][c] + lq[1][c] + lq[2][c] + lq[3][c]);
    }
}

__global__ void k_bnparams(float* __restrict__ stats, const float* __restrict__ g,
                           const float* __restrict__ be, float n) {
    int c = threadIdx.x;  // 64 threads
    float mu = stats[c] / n;
    float var = stats[HF + c] / n - mu * mu;  // biased var, matches jnp.var(0)
    float a = g[c] * rsqrtf(var + 1e-5f);
    stats[128 + c] = a;
    stats[192 + c] = be[c] - mu * a;
}

__global__ void k_bnapply(const float* __restrict__ A, const float* __restrict__ rdeg,
                          const float* __restrict__ stats, float* __restrict__ X, int n) {
    int t = blockIdx.x * 256 + threadIdx.x;
    if (t >= n * HF) return;
    int c = t & 63, r = t >> 6;
    float v = rdeg[r] * A[t];
    X[t] = fmaxf(fmaf(stats[128 + c], v, stats[192 + c]), 0.0f);
}

// Layer 3: BN+ReLU fused directly into the pool atomics (X never materialized).
__global__ void k_bnapply_pool(const float* __restrict__ A, const float* __restrict__ rdeg,
                               const float* __restrict__ stats, const int* __restrict__ batch,
                               float* __restrict__ pool, int n) {
    int t = blockIdx.x * 256 + threadIdx.x;
    if (t >= n * HF) return;
    int c = t & 63, r = t >> 6;
    float v = rdeg[r] * A[t];
    float relu = fmaxf(fmaf(stats[128 + c], v, stats[192 + c]), 0.0f);
    atomicAdd(&pool[(size_t)batch[r] * HF + c], relu);
}

__global__ void k_cls(const float* __restrict__ pool, const float* __restrict__ Wc1,
                      const float* __restrict__ bc1, const float* __restrict__ Wc2,
                      const float* __restrict__ bc2, float* __restrict__ out) {
    __shared__ float pl[HF], hr[HF];
    int g = blockIdx.x, c = threadIdx.x;
    pl[c] = pool[g * HF + c];
    __syncthreads();
    float h = bc1[c];
#pragma unroll
    for (int k = 0; k < HF; ++k) h = fmaf(pl[k], Wc1[c * HF + k], h);
    hr[c] = fmaxf(h, 0.f);
    __syncthreads();
    if (c < OUTF) {
        float o = bc2[c];
#pragma unroll
        for (int k = 0; k < HF; ++k) o = fmaf(hr[k], Wc2[c * HF + k], o);
        out[g * OUTF + c] = o;
    }
}

extern "C" void kernel_launch(void* const* d_in, const int* in_sizes, int n_in,
                              void* d_out, int out_size, void* d_ws, size_t ws_size,
                              hipStream_t stream) {
    const float* x = (const float*)d_in[0];
    const int* edge = (const int*)d_in[1];
    const int* batch = (const int*)d_in[2];
    const float* W1 = (const float*)d_in[3];
    const float* b1 = (const float*)d_in[4];
    const float* g1 = (const float*)d_in[5];
    const float* be1 = (const float*)d_in[6];
    const float* W2 = (const float*)d_in[7];
    const float* b2 = (const float*)d_in[8];
    const float* g2 = (const float*)d_in[9];
    const float* be2 = (const float*)d_in[10];
    const float* W3 = (const float*)d_in[11];
    const float* b3 = (const float*)d_in[12];
    const float* g3 = (const float*)d_in[13];
    const float* be3 = (const float*)d_in[14];
    const float* Wc1 = (const float*)d_in[15];
    const float* bc1 = (const float*)d_in[16];
    const float* Wc2 = (const float*)d_in[17];
    const float* bc2 = (const float*)d_in[18];
    float* out = (float*)d_out;

    const int* src = edge;
    const int* dst = edge + NE;

    const size_t N64 = (size_t)NN * HF;
    float* ws = (float*)d_ws;
    float* buf0 = ws;                      // N*64  (Hs; also BN output X)
    float* buf1 = ws + N64;                // N*64  (A aggregation)
    float* rdeg = ws + 2 * N64;            // N
    float* stats = rdeg + NN;              // 256: sum|sumsq|a|b2
    float* pool = stats + 256;             // NG*64
    int* cnt = (int*)(pool + NG * HF);     // N   (histogram, then scatter cursor)
    int* ro = cnt + NN;                    // N+1 (CSR row offsets by dst)
    int* bsum = ro + NN + 1;               // 128
    int* ss = bsum + 128;                  // E   (src ids sorted by dst)

    // ---- CSR build (once per call) ----
    hipMemsetAsync(cnt, 0, NN * sizeof(int), stream);
    k_hist<<<(NE + 255) / 256, 256, 0, stream>>>(dst, cnt, NE);
    k_rdegi<<<(NN + 255) / 256, 256, 0, stream>>>(cnt, rdeg, NN);
    const int nblk = (NN + 1023) / 1024;  // 98
    k_scan1<<<nblk, 256, 0, stream>>>(cnt, ro, bsum, NN);
    k_scan2<<<1, 128, 0, stream>>>(bsum, nblk);
    k_scan3<<<(NN + 255) / 256, 256, 0, stream>>>(ro, cnt, bsum, NN, NE);
    k_scatter<<<(NE + 255) / 256, 256, 0, stream>>>(src, dst, cnt, ss, NE);

    hipMemsetAsync(pool, 0, (size_t)NG * HF * sizeof(float), stream);

    const float* W[3] = {W1, W2, W3};
    const float* bb[3] = {b1, b2, b3};
    const float* gg[3] = {g1, g2, g3};
    const float* bebe[3] = {be1, be2, be3};

    for (int l = 0; l < 3; ++l) {
        if (l == 0)
            k_gemm<INF_><<<(NN + 255) / 256, 256, 0, stream>>>(x, W[0], bb[0], rdeg, buf0, NN);
        else
            k_gemm<HF><<<(NN + 255) / 256, 256, 0, stream>>>(buf0, W[l], bb[l], rdeg, buf0, NN);
        k_agg<<<(NN + 3) / 4, 256, 0, stream>>>(ro, ss, buf0, buf1, NN);
        hipMemsetAsync(stats, 0, 128 * sizeof(float), stream);
        k_stats<<<1024, 256, 0, stream>>>(buf1, rdeg, stats, NN);
        k_bnparams<<<1, 64, 0, stream>>>(stats, gg[l], bebe[l], (float)NN);
        if (l < 2)
            k_bnapply<<<((int)N64 + 255) / 256, 256, 0, stream>>>(buf1, rdeg, stats, buf0, NN);
        else
            k_bnapply_pool<<<((int)N64 + 255) / 256, 256, 0, stream>>>(buf1, rdeg, stats, batch, pool, NN);
    }

    k_cls<<<NG, HF, 0, stream>>>(pool, Wc1, bc1, Wc2, bc2, out);
}